// Round 1
// baseline (656.978 us; speedup 1.0000x reference)
//
#include <hip/hip_runtime.h>
#include <hip/hip_bf16.h>

// ---------------------------------------------------------------------------
// TokenCrossModule on MI355X.
//   GEMM1 (split-K, bf16-split MFMA)  -> partials in d_out (reused as scratch)
//   k_mid: reduce + b1 + GELU + LayerNorm -> bf16 hi/lo planes + row means (ws)
//   k_se : tiny squeeze-excite -> sigmoid scales (ws)
//   GEMM2 (bf16-split MFMA) epilogue: sig[row]*acc + b2[d], permuted store -> d_out
// Numerics: fp32 value v = hi + lo (bf16 each); v*w ~ hi*wh + hi*wl + lo*wh,
// missing lo*wl ~ 2^-16 relative -> output absmax err ~1e-4.
// ---------------------------------------------------------------------------

typedef unsigned short u16;
typedef unsigned int u32;
typedef __attribute__((ext_vector_type(4))) float f32x4;
typedef __attribute__((ext_vector_type(8))) __bf16 bf16x8;
typedef __attribute__((ext_vector_type(4))) u16 u16x4;
typedef __attribute__((ext_vector_type(8))) u16 u16x8;

#define MFMA16(A, B, C) __builtin_amdgcn_mfma_f32_16x16x32_bf16((A), (B), (C), 0, 0, 0)

// LDS layout (ushort units). A planes: 128 rows x 72 (64 + 8 pad) ; B: 256 x 72.
#define AH 0
#define AL 9216
#define BHo 18432
#define BLo 36864
#define LDSN 55296

__device__ __forceinline__ void split2(float f, u16& hi, u16& lo) {
  u32 u = __builtin_bit_cast(u32, f);
  u32 uh = u & 0xFFFF0000u;            // truncated bf16 hi (residual exact)
  hi = (u16)(uh >> 16);
  float r = f - __builtin_bit_cast(float, uh);
  u32 v = __builtin_bit_cast(u32, r);  // RNE bf16 of residual
  v += 0x7FFFu + ((v >> 16) & 1u);
  lo = (u16)(v >> 16);
}

__device__ __forceinline__ float gelu_exact(float x) {
  return 0.5f * x * (1.0f + erff(x * 0.70710678118654752f));
}

// ------------------------- GEMM1: h_pre partials ---------------------------
// grid (4, 64): blockIdx.x = n-tile (256 cols of e), blockIdx.y = k-split slice
// part[ks][row(0..127)][col(0..1023)] lives in d_out.
__global__ __launch_bounds__(512, 2) void k_gemm1(const float* __restrict__ x,
                                                  const float* __restrict__ w1,
                                                  float* __restrict__ part) {
  __shared__ u16 sm[LDSN];
  const int t = threadIdx.x;
  const int wv = t >> 6, ln = t & 63;
  const int lr = ln & 15, lq = ln >> 4;
  const int wr = wv >> 2, wc = wv & 3;  // wave -> (row-half, col-quarter)
  const int n0 = blockIdx.x * 256;
  const int ks = blockIdx.y;

  f32x4 acc[4][4];
#pragma unroll
  for (int i = 0; i < 4; ++i)
#pragma unroll
    for (int j = 0; j < 4; ++j) acc[i][j] = (f32x4){0.f, 0.f, 0.f, 0.f};

  for (int it = 0; it < 16; ++it) {
    const int k0 = ks * 1024 + it * 64;      // global k (= d index)
    const int sidx = k0 >> 7, c0 = k0 & 127; // permuted-x addressing
    // stage A = xg tile [128 rows][64 k] fp32 -> bf16 hi/lo planes
#pragma unroll
    for (int j = 0; j < 4; ++j) {
      const int i = t + 512 * j;
      const int ar = i >> 4, c4 = i & 15;
      const f32x4 v = *(const f32x4*)(x + (ar >> 3) * 524288 + sidx * 1024 +
                                      (ar & 7) * 128 + c0 + c4 * 4);
      u16x4 hi, lo;
#pragma unroll
      for (int c = 0; c < 4; ++c) { u16 h_, l_; split2(v[c], h_, l_); hi[c] = h_; lo[c] = l_; }
      *(u16x4*)&sm[AH + ar * 72 + c4 * 4] = hi;
      *(u16x4*)&sm[AL + ar * 72 + c4 * 4] = lo;
    }
    // stage B = W1 tile [256 n-rows][64 k]
#pragma unroll
    for (int j = 0; j < 8; ++j) {
      const int i = t + 512 * j;
      const int br = i >> 4, c4 = i & 15;
      const f32x4 v = *(const f32x4*)(w1 + (size_t)(n0 + br) * 65536 + k0 + c4 * 4);
      u16x4 hi, lo;
#pragma unroll
      for (int c = 0; c < 4; ++c) { u16 h_, l_; split2(v[c], h_, l_); hi[c] = h_; lo[c] = l_; }
      *(u16x4*)&sm[BHo + br * 72 + c4 * 4] = hi;
      *(u16x4*)&sm[BLo + br * 72 + c4 * 4] = lo;
    }
    __syncthreads();
#pragma unroll
    for (int ku = 0; ku < 2; ++ku) {
      bf16x8 ah[4], alo[4], bh[4], bl[4];
#pragma unroll
      for (int f = 0; f < 4; ++f) {
        const int ra = (wr * 64 + f * 16 + lr) * 72 + ku * 32 + lq * 8;
        ah[f] = __builtin_bit_cast(bf16x8, *(const u16x8*)&sm[AH + ra]);
        alo[f] = __builtin_bit_cast(bf16x8, *(const u16x8*)&sm[AL + ra]);
        const int rb = (wc * 64 + f * 16 + lr) * 72 + ku * 32 + lq * 8;
        bh[f] = __builtin_bit_cast(bf16x8, *(const u16x8*)&sm[BHo + rb]);
        bl[f] = __builtin_bit_cast(bf16x8, *(const u16x8*)&sm[BLo + rb]);
      }
#pragma unroll
      for (int mf = 0; mf < 4; ++mf)
#pragma unroll
        for (int nf = 0; nf < 4; ++nf) {
          acc[mf][nf] = MFMA16(ah[mf], bh[nf], acc[mf][nf]);
          acc[mf][nf] = MFMA16(ah[mf], bl[nf], acc[mf][nf]);
          acc[mf][nf] = MFMA16(alo[mf], bh[nf], acc[mf][nf]);
        }
    }
    __syncthreads();
  }
#pragma unroll
  for (int mf = 0; mf < 4; ++mf)
#pragma unroll
    for (int nf = 0; nf < 4; ++nf) {
      const int col = n0 + wc * 64 + nf * 16 + lr;
#pragma unroll
      for (int rg = 0; rg < 4; ++rg) {
        const int row = wr * 64 + mf * 16 + lq * 4 + rg;
        part[(size_t)(ks * 128 + row) * 1024 + col] = acc[mf][nf][rg];
      }
    }
}

// --------------- reduce partials + bias + GELU + LayerNorm -----------------
// grid 128 (one block per (b,g) row), 256 threads (4 elems each).
__global__ __launch_bounds__(256) void k_mid(const float* __restrict__ part,
                                             const float* __restrict__ b1,
                                             const float* __restrict__ lng,
                                             const float* __restrict__ lnb,
                                             u16* __restrict__ hhi, u16* __restrict__ hlo,
                                             float* __restrict__ mrow) {
  const int r = blockIdx.x, t = threadIdx.x;
  const float* p = part + r * 1024 + t * 4;
  f32x4 a = (f32x4){0.f, 0.f, 0.f, 0.f};
#pragma unroll 8
  for (int ks = 0; ks < 64; ++ks) a += *(const f32x4*)(p + (size_t)ks * 131072);
  const f32x4 bb = *(const f32x4*)(b1 + t * 4);
  f32x4 v;
#pragma unroll
  for (int c = 0; c < 4; ++c) v[c] = gelu_exact(a[c] + bb[c]);

  float s1 = v[0] + v[1] + v[2] + v[3];
  float s2 = v[0] * v[0] + v[1] * v[1] + v[2] * v[2] + v[3] * v[3];
#pragma unroll
  for (int o = 32; o; o >>= 1) { s1 += __shfl_xor(s1, o); s2 += __shfl_xor(s2, o); }
  __shared__ float red[16];
  const int wv = t >> 6, ln = t & 63;
  if (ln == 0) { red[wv] = s1; red[8 + wv] = s2; }
  __syncthreads();
  s1 = red[0] + red[1] + red[2] + red[3];
  s2 = red[8] + red[9] + red[10] + red[11];
  const float mu = s1 * (1.f / 1024.f);
  const float var = s2 * (1.f / 1024.f) - mu * mu;
  const float rstd = rsqrtf(var + 1e-5f);
  const f32x4 g4 = *(const f32x4*)(lng + t * 4);
  const f32x4 o4 = *(const f32x4*)(lnb + t * 4);
  f32x4 h;
#pragma unroll
  for (int c = 0; c < 4; ++c) h[c] = (v[c] - mu) * rstd * g4[c] + o4[c];

  float s3 = h[0] + h[1] + h[2] + h[3];
#pragma unroll
  for (int o = 32; o; o >>= 1) s3 += __shfl_xor(s3, o);
  __syncthreads();
  if (ln == 0) red[wv] = s3;
  __syncthreads();
  if (t == 0) mrow[r] = (red[0] + red[1] + red[2] + red[3]) * (1.f / 1024.f);

  u16x4 uh, ul;
#pragma unroll
  for (int c = 0; c < 4; ++c) { u16 h_, l_; split2(h[c], h_, l_); uh[c] = h_; ul[c] = l_; }
  *(u16x4*)(hhi + r * 1024 + t * 4) = uh;
  *(u16x4*)(hlo + r * 1024 + t * 4) = ul;
}

// --------------------------- squeeze-excite --------------------------------
__global__ void k_se(const float* __restrict__ mrow, const float* __restrict__ w1,
                     const float* __restrict__ g1, const float* __restrict__ o1,
                     const float* __restrict__ m1, const float* __restrict__ v1,
                     const float* __restrict__ w2, const float* __restrict__ g2,
                     const float* __restrict__ o2, const float* __restrict__ m2,
                     const float* __restrict__ v2, float* __restrict__ sig) {
  const int t = threadIdx.x;
  if (t >= 16) return;
  float m[8];
#pragma unroll
  for (int g = 0; g < 8; ++g) m[g] = mrow[t * 8 + g];
  float z1[4];
#pragma unroll
  for (int i = 0; i < 4; ++i) {
    float s = 0.f;
#pragma unroll
    for (int g = 0; g < 8; ++g) s += m[g] * w1[i * 8 + g];
    s = (s - m1[i]) * rsqrtf(v1[i] + 1e-5f) * g1[i] + o1[i];
    z1[i] = gelu_exact(s);
  }
#pragma unroll
  for (int o = 0; o < 8; ++o) {
    float s = 0.f;
#pragma unroll
    for (int i = 0; i < 4; ++i) s += z1[i] * w2[o * 4 + i];
    s = (s - m2[o]) * rsqrtf(v2[o] + 1e-5f) * g2[o] + o2[o];
    sig[t * 8 + o] = 1.f / (1.f + expf(-s));
  }
}

// ------------------------- GEMM2 + epilogue --------------------------------
// grid 256: blockIdx.x = n-tile (256 cols of din). K = 1024 full.
__global__ __launch_bounds__(512, 2) void k_gemm2(const u16* __restrict__ hhi,
                                                  const u16* __restrict__ hlo,
                                                  const float* __restrict__ w2,
                                                  const float* __restrict__ b2,
                                                  const float* __restrict__ sig,
                                                  float* __restrict__ out) {
  __shared__ u16 sm[LDSN];
  const int t = threadIdx.x;
  const int wv = t >> 6, ln = t & 63;
  const int lr = ln & 15, lq = ln >> 4;
  const int wr = wv >> 2, wc = wv & 3;
  const int n0 = blockIdx.x * 256;

  f32x4 acc[4][4];
#pragma unroll
  for (int i = 0; i < 4; ++i)
#pragma unroll
    for (int j = 0; j < 4; ++j) acc[i][j] = (f32x4){0.f, 0.f, 0.f, 0.f};

  for (int it = 0; it < 16; ++it) {
    const int k0 = it * 64;
    // stage A from precomputed bf16 planes (no conversion)
#pragma unroll
    for (int j = 0; j < 2; ++j) {
      const int i = t + 512 * j;
      const int ar = i >> 3, c8 = i & 7;
      *(u16x8*)&sm[AH + ar * 72 + c8 * 8] = *(const u16x8*)(hhi + ar * 1024 + k0 + c8 * 8);
      *(u16x8*)&sm[AL + ar * 72 + c8 * 8] = *(const u16x8*)(hlo + ar * 1024 + k0 + c8 * 8);
    }
    // stage B = W2 tile [256 n-rows][64 k] fp32 -> bf16 hi/lo
#pragma unroll
    for (int j = 0; j < 8; ++j) {
      const int i = t + 512 * j;
      const int br = i >> 4, c4 = i & 15;
      const f32x4 v = *(const f32x4*)(w2 + (size_t)(n0 + br) * 1024 + k0 + c4 * 4);
      u16x4 hi, lo;
#pragma unroll
      for (int c = 0; c < 4; ++c) { u16 h_, l_; split2(v[c], h_, l_); hi[c] = h_; lo[c] = l_; }
      *(u16x4*)&sm[BHo + br * 72 + c4 * 4] = hi;
      *(u16x4*)&sm[BLo + br * 72 + c4 * 4] = lo;
    }
    __syncthreads();
#pragma unroll
    for (int ku = 0; ku < 2; ++ku) {
      bf16x8 ah[4], alo[4], bh[4], bl[4];
#pragma unroll
      for (int f = 0; f < 4; ++f) {
        const int ra = (wr * 64 + f * 16 + lr) * 72 + ku * 32 + lq * 8;
        ah[f] = __builtin_bit_cast(bf16x8, *(const u16x8*)&sm[AH + ra]);
        alo[f] = __builtin_bit_cast(bf16x8, *(const u16x8*)&sm[AL + ra]);
        const int rb = (wc * 64 + f * 16 + lr) * 72 + ku * 32 + lq * 8;
        bh[f] = __builtin_bit_cast(bf16x8, *(const u16x8*)&sm[BHo + rb]);
        bl[f] = __builtin_bit_cast(bf16x8, *(const u16x8*)&sm[BLo + rb]);
      }
#pragma unroll
      for (int mf = 0; mf < 4; ++mf)
#pragma unroll
        for (int nf = 0; nf < 4; ++nf) {
          acc[mf][nf] = MFMA16(ah[mf], bh[nf], acc[mf][nf]);
          acc[mf][nf] = MFMA16(ah[mf], bl[nf], acc[mf][nf]);
          acc[mf][nf] = MFMA16(alo[mf], bh[nf], acc[mf][nf]);
        }
    }
    __syncthreads();
  }
  // epilogue: y = sig[row]*acc + b2[d], permuted store into [b,s,e]
  float sgv[4][4];
#pragma unroll
  for (int mf = 0; mf < 4; ++mf)
#pragma unroll
    for (int rg = 0; rg < 4; ++rg) sgv[mf][rg] = sig[wr * 64 + mf * 16 + lq * 4 + rg];
#pragma unroll
  for (int nf = 0; nf < 4; ++nf) {
    const int d = n0 + wc * 64 + nf * 16 + lr;
    const float b2v = b2[d];
    const int sidx = d >> 7, c = d & 127;
#pragma unroll
    for (int mf = 0; mf < 4; ++mf)
#pragma unroll
      for (int rg = 0; rg < 4; ++rg) {
        const int row = wr * 64 + mf * 16 + lq * 4 + rg;
        out[(size_t)(row >> 3) * 524288 + sidx * 1024 + (row & 7) * 128 + c] =
            sgv[mf][rg] * acc[mf][nf][rg] + b2v;
      }
  }
}

// ---------------------------------------------------------------------------
extern "C" void kernel_launch(void* const* d_in, const int* in_sizes, int n_in,
                              void* d_out, int out_size, void* d_ws, size_t ws_size,
                              hipStream_t stream) {
  (void)in_sizes; (void)n_in; (void)out_size; (void)ws_size;
  const float* x = (const float*)d_in[0];
  const float* W1 = (const float*)d_in[1];
  const float* b1 = (const float*)d_in[2];
  const float* W2 = (const float*)d_in[3];
  const float* b2 = (const float*)d_in[4];
  const float* lng = (const float*)d_in[5];
  const float* lnb = (const float*)d_in[6];
  const float* sw1 = (const float*)d_in[7];
  const float* bn1g = (const float*)d_in[8];
  const float* bn1b = (const float*)d_in[9];
  const float* bn1m = (const float*)d_in[10];
  const float* bn1v = (const float*)d_in[11];
  const float* sw2 = (const float*)d_in[12];
  const float* bn2g = (const float*)d_in[13];
  const float* bn2b = (const float*)d_in[14];
  const float* bn2m = (const float*)d_in[15];
  const float* bn2v = (const float*)d_in[16];
  float* out = (float*)d_out;

  // d_out doubles as the split-K partial buffer (64*128*1024 floats == out_size).
  float* part = out;
  u16* hhi = (u16*)d_ws;                 // 128*1024 bf16 hi
  u16* hlo = hhi + 131072;               // 128*1024 bf16 lo
  float* mrow = (float*)(hlo + 131072);  // 128 row means
  float* sig = mrow + 128;               // 128 sigmoid scales

  k_gemm1<<<dim3(4, 64), 512, 0, stream>>>(x, W1, part);
  k_mid<<<128, 256, 0, stream>>>(part, b1, lng, lnb, hhi, hlo, mrow);
  k_se<<<1, 64, 0, stream>>>(mrow, sw1, bn1g, bn1b, bn1m, bn1v, sw2, bn2g, bn2b, bn2m, bn2v, sig);
  k_gemm2<<<256, 512, 0, stream>>>(hhi, hlo, W2, b2, sig, out);
}

// Round 6
// 651.226 us; speedup vs baseline: 1.0088x; 1.0088x over previous
//
#include <hip/hip_runtime.h>
#include <hip/hip_bf16.h>

// ---------------------------------------------------------------------------
// TokenCrossModule on MI355X — round 6: BISECT.
//   k_gemm1 / k_mid / k_se: byte-exact round-1 (PASSED, absmax 0.0078).
//   k_gemm2: round-2 geometry (128x128, BK=32, 4 waves, PAD=40) + round-1
//            split2 conversion.
// If this passes -> round-2 k_gemm1 retile was the bug. If it fails with
// absmax ~5 -> round-2 k_gemm2 retile is the bug.
// ---------------------------------------------------------------------------

typedef unsigned short u16;
typedef unsigned int u32;
typedef __attribute__((ext_vector_type(4))) float f32x4;
typedef __attribute__((ext_vector_type(8))) __bf16 bf16x8;
typedef __attribute__((ext_vector_type(4))) u16 u16x4;
typedef __attribute__((ext_vector_type(8))) u16 u16x8;

#define MFMA16(A, B, C) __builtin_amdgcn_mfma_f32_16x16x32_bf16((A), (B), (C), 0, 0, 0)

// Round-1 k_gemm1 LDS layout (u16 units). A planes: 128 x 72 ; B: 256 x 72.
#define AH 0
#define AL 9216
#define BHo 18432
#define BLo 36864

// Round-2-geometry k_gemm2 LDS layout (u16 units): 4 planes of 128 x 40.
#define PAD2 40
#define A2H 0
#define A2L 5120
#define B2H 10240
#define B2L 15360

__device__ __forceinline__ void split2(float f, u16& hi, u16& lo) {
  u32 u = __builtin_bit_cast(u32, f);
  u32 uh = u & 0xFFFF0000u;            // truncated bf16 hi (residual exact)
  hi = (u16)(uh >> 16);
  float r = f - __builtin_bit_cast(float, uh);
  u32 v = __builtin_bit_cast(u32, r);  // RNE bf16 of residual
  v += 0x7FFFu + ((v >> 16) & 1u);
  lo = (u16)(v >> 16);
}

__device__ __forceinline__ float gelu_exact(float x) {
  return 0.5f * x * (1.0f + erff(x * 0.70710678118654752f));
}

// ------------------------- GEMM1: h_pre partials (round-1 exact) ----------
// grid (4, 64): blockIdx.x = n-tile (256 cols of e), blockIdx.y = k-split slice
// part[ks][row(0..127)][col(0..1023)] lives in d_out.
__global__ __launch_bounds__(512, 2) void k_gemm1(const float* __restrict__ x,
                                                  const float* __restrict__ w1,
                                                  float* __restrict__ part) {
  __shared__ u16 sm[55296];
  const int t = threadIdx.x;
  const int wv = t >> 6, ln = t & 63;
  const int lr = ln & 15, lq = ln >> 4;
  const int wr = wv >> 2, wc = wv & 3;  // wave -> (row-half, col-quarter)
  const int n0 = blockIdx.x * 256;
  const int ks = blockIdx.y;

  f32x4 acc[4][4];
#pragma unroll
  for (int i = 0; i < 4; ++i)
#pragma unroll
    for (int j = 0; j < 4; ++j) acc[i][j] = (f32x4){0.f, 0.f, 0.f, 0.f};

  for (int it = 0; it < 16; ++it) {
    const int k0 = ks * 1024 + it * 64;      // global k (= d index)
    const int sidx = k0 >> 7, c0 = k0 & 127; // permuted-x addressing
    // stage A = xg tile [128 rows][64 k] fp32 -> bf16 hi/lo planes
#pragma unroll
    for (int j = 0; j < 4; ++j) {
      const int i = t + 512 * j;
      const int ar = i >> 4, c4 = i & 15;
      const f32x4 v = *(const f32x4*)(x + (ar >> 3) * 524288 + sidx * 1024 +
                                      (ar & 7) * 128 + c0 + c4 * 4);
      u16x4 hi, lo;
#pragma unroll
      for (int c = 0; c < 4; ++c) { u16 h_, l_; split2(v[c], h_, l_); hi[c] = h_; lo[c] = l_; }
      *(u16x4*)&sm[AH + ar * 72 + c4 * 4] = hi;
      *(u16x4*)&sm[AL + ar * 72 + c4 * 4] = lo;
    }
    // stage B = W1 tile [256 n-rows][64 k]
#pragma unroll
    for (int j = 0; j < 8; ++j) {
      const int i = t + 512 * j;
      const int br = i >> 4, c4 = i & 15;
      const f32x4 v = *(const f32x4*)(w1 + (size_t)(n0 + br) * 65536 + k0 + c4 * 4);
      u16x4 hi, lo;
#pragma unroll
      for (int c = 0; c < 4; ++c) { u16 h_, l_; split2(v[c], h_, l_); hi[c] = h_; lo[c] = l_; }
      *(u16x4*)&sm[BHo + br * 72 + c4 * 4] = hi;
      *(u16x4*)&sm[BLo + br * 72 + c4 * 4] = lo;
    }
    __syncthreads();
#pragma unroll
    for (int ku = 0; ku < 2; ++ku) {
      bf16x8 ah[4], alo[4], bh[4], bl[4];
#pragma unroll
      for (int f = 0; f < 4; ++f) {
        const int ra = (wr * 64 + f * 16 + lr) * 72 + ku * 32 + lq * 8;
        ah[f] = __builtin_bit_cast(bf16x8, *(const u16x8*)&sm[AH + ra]);
        alo[f] = __builtin_bit_cast(bf16x8, *(const u16x8*)&sm[AL + ra]);
        const int rb = (wc * 64 + f * 16 + lr) * 72 + ku * 32 + lq * 8;
        bh[f] = __builtin_bit_cast(bf16x8, *(const u16x8*)&sm[BHo + rb]);
        bl[f] = __builtin_bit_cast(bf16x8, *(const u16x8*)&sm[BLo + rb]);
      }
#pragma unroll
      for (int mf = 0; mf < 4; ++mf)
#pragma unroll
        for (int nf = 0; nf < 4; ++nf) {
          acc[mf][nf] = MFMA16(ah[mf], bh[nf], acc[mf][nf]);
          acc[mf][nf] = MFMA16(ah[mf], bl[nf], acc[mf][nf]);
          acc[mf][nf] = MFMA16(alo[mf], bh[nf], acc[mf][nf]);
        }
    }
    __syncthreads();
  }
#pragma unroll
  for (int mf = 0; mf < 4; ++mf)
#pragma unroll
    for (int nf = 0; nf < 4; ++nf) {
      const int col = n0 + wc * 64 + nf * 16 + lr;
#pragma unroll
      for (int rg = 0; rg < 4; ++rg) {
        const int row = wr * 64 + mf * 16 + lq * 4 + rg;
        part[(size_t)(ks * 128 + row) * 1024 + col] = acc[mf][nf][rg];
      }
    }
}

// --------------- reduce partials + bias + GELU + LayerNorm (round-1) -------
// grid 128 (one block per (b,g) row), 256 threads (4 elems each).
__global__ __launch_bounds__(256) void k_mid(const float* __restrict__ part,
                                             const float* __restrict__ b1,
                                             const float* __restrict__ lng,
                                             const float* __restrict__ lnb,
                                             u16* __restrict__ hhi, u16* __restrict__ hlo,
                                             float* __restrict__ mrow) {
  const int r = blockIdx.x, t = threadIdx.x;
  const float* p = part + r * 1024 + t * 4;
  f32x4 a = (f32x4){0.f, 0.f, 0.f, 0.f};
#pragma unroll 8
  for (int ks = 0; ks < 64; ++ks) a += *(const f32x4*)(p + (size_t)ks * 131072);
  const f32x4 bb = *(const f32x4*)(b1 + t * 4);
  f32x4 v;
#pragma unroll
  for (int c = 0; c < 4; ++c) v[c] = gelu_exact(a[c] + bb[c]);

  float s1 = v[0] + v[1] + v[2] + v[3];
  float s2 = v[0] * v[0] + v[1] * v[1] + v[2] * v[2] + v[3] * v[3];
#pragma unroll
  for (int o = 32; o; o >>= 1) { s1 += __shfl_xor(s1, o); s2 += __shfl_xor(s2, o); }
  __shared__ float red[16];
  const int wv = t >> 6, ln = t & 63;
  if (ln == 0) { red[wv] = s1; red[8 + wv] = s2; }
  __syncthreads();
  s1 = red[0] + red[1] + red[2] + red[3];
  s2 = red[8] + red[9] + red[10] + red[11];
  const float mu = s1 * (1.f / 1024.f);
  const float var = s2 * (1.f / 1024.f) - mu * mu;
  const float rstd = rsqrtf(var + 1e-5f);
  const f32x4 g4 = *(const f32x4*)(lng + t * 4);
  const f32x4 o4 = *(const f32x4*)(lnb + t * 4);
  f32x4 h;
#pragma unroll
  for (int c = 0; c < 4; ++c) h[c] = (v[c] - mu) * rstd * g4[c] + o4[c];

  float s3 = h[0] + h[1] + h[2] + h[3];
#pragma unroll
  for (int o = 32; o; o >>= 1) s3 += __shfl_xor(s3, o);
  __syncthreads();
  if (ln == 0) red[wv] = s3;
  __syncthreads();
  if (t == 0) mrow[r] = (red[0] + red[1] + red[2] + red[3]) * (1.f / 1024.f);

  u16x4 uh, ul;
#pragma unroll
  for (int c = 0; c < 4; ++c) { u16 h_, l_; split2(h[c], h_, l_); uh[c] = h_; ul[c] = l_; }
  *(u16x4*)(hhi + r * 1024 + t * 4) = uh;
  *(u16x4*)(hlo + r * 1024 + t * 4) = ul;
}

// --------------------------- squeeze-excite (round-1) ----------------------
__global__ void k_se(const float* __restrict__ mrow, const float* __restrict__ w1,
                     const float* __restrict__ g1, const float* __restrict__ o1,
                     const float* __restrict__ m1, const float* __restrict__ v1,
                     const float* __restrict__ w2, const float* __restrict__ g2,
                     const float* __restrict__ o2, const float* __restrict__ m2,
                     const float* __restrict__ v2, float* __restrict__ sig) {
  const int t = threadIdx.x;
  if (t >= 16) return;
  float m[8];
#pragma unroll
  for (int g = 0; g < 8; ++g) m[g] = mrow[t * 8 + g];
  float z1[4];
#pragma unroll
  for (int i = 0; i < 4; ++i) {
    float s = 0.f;
#pragma unroll
    for (int g = 0; g < 8; ++g) s += m[g] * w1[i * 8 + g];
    s = (s - m1[i]) * rsqrtf(v1[i] + 1e-5f) * g1[i] + o1[i];
    z1[i] = gelu_exact(s);
  }
#pragma unroll
  for (int o = 0; o < 8; ++o) {
    float s = 0.f;
#pragma unroll
    for (int i = 0; i < 4; ++i) s += z1[i] * w2[o * 4 + i];
    s = (s - m2[o]) * rsqrtf(v2[o] + 1e-5f) * g2[o] + o2[o];
    sig[t * 8 + o] = 1.f / (1.f + expf(-s));
  }
}

// ------------------- GEMM2 + epilogue (round-2 geometry) -------------------
// grid 512: blockIdx.x = n-tile (128 cols of din). K = 1024 full.
__global__ __launch_bounds__(256, 2) void k_gemm2(const u16* __restrict__ hhi,
                                                  const u16* __restrict__ hlo,
                                                  const float* __restrict__ w2,
                                                  const float* __restrict__ b2,
                                                  const float* __restrict__ sig,
                                                  float* __restrict__ out) {
  __shared__ u16 sm[20480];
  const int t = threadIdx.x;
  const int wv = t >> 6, ln = t & 63;
  const int lr = ln & 15, lq = ln >> 4;
  const int wr = wv >> 1, wc = wv & 1;
  const int n0 = blockIdx.x * 128;
  const int srow = t >> 3, sc = (t & 7) * 4;      // B staging
  const int arow = t >> 2, ac = (t & 3) * 8;      // A staging (u16x8)

  f32x4 acc[4][4];
#pragma unroll
  for (int i = 0; i < 4; ++i)
#pragma unroll
    for (int j = 0; j < 4; ++j) acc[i][j] = (f32x4){0.f, 0.f, 0.f, 0.f};

  for (int it = 0; it < 32; ++it) {
    const int k0 = it * 32;
    // A from precomputed bf16 planes (no conversion)
#pragma unroll
    for (int j = 0; j < 2; ++j) {
      const int row = arow + 64 * j;
      *(u16x8*)&sm[A2H + row * PAD2 + ac] = *(const u16x8*)(hhi + row * 1024 + k0 + ac);
      *(u16x8*)&sm[A2L + row * PAD2 + ac] = *(const u16x8*)(hlo + row * 1024 + k0 + ac);
    }
    // B = W2 tile [128 n-rows][32 k] fp32 -> bf16 hi/lo via split2
#pragma unroll
    for (int j = 0; j < 4; ++j) {
      const int row = srow + 32 * j;
      const f32x4 vb = *(const f32x4*)(w2 + (size_t)(n0 + row) * 1024 + k0 + sc);
      u16x4 hi, lo;
#pragma unroll
      for (int c = 0; c < 4; ++c) { u16 h_, l_; split2(vb[c], h_, l_); hi[c] = h_; lo[c] = l_; }
      *(u16x4*)&sm[B2H + row * PAD2 + sc] = hi;
      *(u16x4*)&sm[B2L + row * PAD2 + sc] = lo;
    }
    __syncthreads();
    bf16x8 ah[4], al[4];
#pragma unroll
    for (int f = 0; f < 4; ++f) {
      const int ra = (wr * 64 + f * 16 + lr) * PAD2 + lq * 8;
      ah[f] = __builtin_bit_cast(bf16x8, *(const u16x8*)&sm[A2H + ra]);
      al[f] = __builtin_bit_cast(bf16x8, *(const u16x8*)&sm[A2L + ra]);
    }
#pragma unroll
    for (int nf = 0; nf < 4; ++nf) {
      const int rb = (wc * 64 + nf * 16 + lr) * PAD2 + lq * 8;
      const bf16x8 bh = __builtin_bit_cast(bf16x8, *(const u16x8*)&sm[B2H + rb]);
      const bf16x8 bl = __builtin_bit_cast(bf16x8, *(const u16x8*)&sm[B2L + rb]);
#pragma unroll
      for (int mf = 0; mf < 4; ++mf) {
        acc[mf][nf] = MFMA16(ah[mf], bh, acc[mf][nf]);
        acc[mf][nf] = MFMA16(ah[mf], bl, acc[mf][nf]);
        acc[mf][nf] = MFMA16(al[mf], bh, acc[mf][nf]);
      }
    }
    __syncthreads();
  }
  // epilogue: y = sig[row]*acc + b2[d], permuted store into [b,s,e]
  float sgv[4][4];
#pragma unroll
  for (int mf = 0; mf < 4; ++mf)
#pragma unroll
    for (int rg = 0; rg < 4; ++rg) sgv[mf][rg] = sig[wr * 64 + mf * 16 + lq * 4 + rg];
#pragma unroll
  for (int nf = 0; nf < 4; ++nf) {
    const int d = n0 + wc * 64 + nf * 16 + lr;
    const float b2v = b2[d];
    const int sidx = d >> 7, c = d & 127;
#pragma unroll
    for (int mf = 0; mf < 4; ++mf)
#pragma unroll
      for (int rg = 0; rg < 4; ++rg) {
        const int row = wr * 64 + mf * 16 + lq * 4 + rg;
        out[(size_t)(row >> 3) * 524288 + sidx * 1024 + (row & 7) * 128 + c] =
            sgv[mf][rg] * acc[mf][nf][rg] + b2v;
      }
  }
}

// ---------------------------------------------------------------------------
extern "C" void kernel_launch(void* const* d_in, const int* in_sizes, int n_in,
                              void* d_out, int out_size, void* d_ws, size_t ws_size,
                              hipStream_t stream) {
  (void)in_sizes; (void)n_in; (void)out_size; (void)ws_size;
  const float* x = (const float*)d_in[0];
  const float* W1 = (const float*)d_in[1];
  const float* b1 = (const float*)d_in[2];
  const float* W2 = (const float*)d_in[3];
  const float* b2 = (const float*)d_in[4];
  const float* lng = (const float*)d_in[5];
  const float* lnb = (const float*)d_in[6];
  const float* sw1 = (const float*)d_in[7];
  const float* bn1g = (const float*)d_in[8];
  const float* bn1b = (const float*)d_in[9];
  const float* bn1m = (const float*)d_in[10];
  const float* bn1v = (const float*)d_in[11];
  const float* sw2 = (const float*)d_in[12];
  const float* bn2g = (const float*)d_in[13];
  const float* bn2b = (const float*)d_in[14];
  const float* bn2m = (const float*)d_in[15];
  const float* bn2v = (const float*)d_in[16];
  float* out = (float*)d_out;

  // d_out doubles as the split-K partial buffer (64*128*1024 floats == out_size).
  float* part = out;
  u16* hhi = (u16*)d_ws;                 // 128*1024 bf16 hi
  u16* hlo = hhi + 131072;               // 128*1024 bf16 lo
  float* mrow = (float*)(hlo + 131072);  // 128 row means
  float* sig = mrow + 128;               // 128 sigmoid scales

  k_gemm1<<<dim3(4, 64), 512, 0, stream>>>(x, W1, part);
  k_mid<<<128, 256, 0, stream>>>(part, b1, lng, lnb, hhi, hlo, mrow);
  k_se<<<1, 64, 0, stream>>>(mrow, sw1, bn1g, bn1b, bn1m, bn1v, sw2, bn2g, bn2b, bn2m, bn2v, sig);
  k_gemm2<<<512, 256, 0, stream>>>(hhi, hlo, W2, b2, sig, out);
}